// Round 11
// baseline (422.311 us; speedup 1.0000x reference)
//
#include <hip/hip_runtime.h>

typedef unsigned short ushort_t;
typedef __attribute__((ext_vector_type(8))) short s8v;
typedef __attribute__((ext_vector_type(4))) float f4v;
typedef __attribute__((ext_vector_type(2))) unsigned int u32x2;
typedef __attribute__((ext_vector_type(4))) unsigned int u32x4;

#define NNODE 4096
#define HID 256
#define CR_L 5.0f      // COORDS_RANGE / L = 15/3
#define ASTR 528       // A-tile row stride in bytes (33*16: aligned, bank-uniform)
#define ASTR16 (16 * ASTR)
#define NSTR 1056      // node-kernel stage-1 stride (66*16)
#define NSTR16 (16 * NSTR)

__device__ __forceinline__ unsigned int cvt2(float lo, float hi) {
  unsigned int r;
  asm("v_cvt_pk_bf16_f32 %0, %1, %2" : "=v"(r) : "v"(lo), "v"(hi));
  return r;  // D[15:0]=lo, D[31:16]=hi, RNE
}
__device__ __forceinline__ ushort_t cvt1(float v) {
  unsigned int r;
  asm("v_cvt_pk_bf16_f32 %0, %1, %2" : "=v"(r) : "v"(v), "v"(v));
  return (ushort_t)r;
}
__device__ __forceinline__ float fast_rcp(float x) {
  float r;
  asm("v_rcp_f32 %0, %1" : "=v"(r) : "v"(x));
  return r;
}
__device__ __forceinline__ float silu_f(float v) { return v * fast_rcp(1.0f + __expf(-v)); }
__device__ __forceinline__ float sigm_f(float v) { return fast_rcp(1.0f + __expf(-v)); }

// ---- fragment-packed B loads (K=256): frag (n16=w*4+nt, ks=q) = 64 contiguous 16B chunks ----
__device__ __forceinline__ void loadB(s8v bd[4], const char* base, int q) {
#pragma unroll
  for (int nt = 0; nt < 4; ++nt)
    bd[nt] = *(const s8v*)(base + nt * 8192 + q * 1024);
}
// K=512 variant (Wn1)
__device__ __forceinline__ void loadBn1(s8v bd[4], const char* base, int q) {
#pragma unroll
  for (int nt = 0; nt < 4; ++nt)
    bd[nt] = *(const s8v*)(base + nt * 16384 + q * 1024);
}
// M=64 MFMA step
__device__ __forceinline__ void mfma_step(const char* Ath, int q, const s8v bc[4], f4v acc[4][4]) {
  s8v a[4];
#pragma unroll
  for (int mt = 0; mt < 4; ++mt)
    a[mt] = *(const s8v*)(Ath + mt * ASTR16 + q * 64);
#pragma unroll
  for (int mt = 0; mt < 4; ++mt)
#pragma unroll
    for (int nt = 0; nt < 4; ++nt)
      acc[mt][nt] = __builtin_amdgcn_mfma_f32_16x16x32_bf16(a[mt], bc[nt], acc[mt][nt], 0, 0, 0);
}
// M=32 MFMA steps (node)
__device__ __forceinline__ void mfma32_n1(const char* Ath, int q, const s8v bc[4], f4v acc[2][4]) {
  s8v a[2];
#pragma unroll
  for (int mt = 0; mt < 2; ++mt)
    a[mt] = *(const s8v*)(Ath + mt * NSTR16 + q * 64);
#pragma unroll
  for (int mt = 0; mt < 2; ++mt)
#pragma unroll
    for (int nt = 0; nt < 4; ++nt)
      acc[mt][nt] = __builtin_amdgcn_mfma_f32_16x16x32_bf16(a[mt], bc[nt], acc[mt][nt], 0, 0, 0);
}
__device__ __forceinline__ void mfma32_a(const char* Ath, int q, const s8v bc[4], f4v acc[2][4]) {
  s8v a[2];
#pragma unroll
  for (int mt = 0; mt < 2; ++mt)
    a[mt] = *(const s8v*)(Ath + mt * ASTR16 + q * 64);
#pragma unroll
  for (int mt = 0; mt < 2; ++mt)
#pragma unroll
    for (int nt = 0; nt < 4; ++nt)
      acc[mt][nt] = __builtin_amdgcn_mfma_f32_16x16x32_bf16(a[mt], bc[nt], acc[mt][nt], 0, 0, 0);
}

// ---------------- weight transpose + bf16 convert (ALL fragment-packed) ----------------
__global__ __launch_bounds__(256) void wconv_kernel(
    const float* __restrict__ We1, const float* __restrict__ We2,
    const float* __restrict__ Wc1, const float* __restrict__ Wn1,
    const float* __restrict__ Wn2, ushort_t* __restrict__ wt) {
  int gid = blockIdx.x * 256 + threadIdx.x;          // < 1376256
  int l = gid / 458752;
  int r = gid - l * 458752;
  float v;
  if (r < 262144) {            // four K=256 mats: We1r, We1c, We2, Wc1
    int m = r >> 16;
    int rr = r & 65535;
    int ki = rr & 7, ln = (rr >> 3) & 63, f = rr >> 9;
    int ks = f & 7, n16 = f >> 3, al = ln & 15, ag = ln >> 4;
    int nn = n16 * 16 + al;
    int kslot = ks * 32 + ag * 8 + ki;
    int k = (m == 3) ? ((kslot & ~63) | ((kslot & 3) << 4) | ((kslot & 63) >> 2)) : kslot;
    if (m == 0)      v = We1[(l * 513 + k) * 256 + nn];
    else if (m == 1) v = We1[(l * 513 + 256 + k) * 256 + nn];
    else if (m == 2) v = We2[(l * 256 + k) * 256 + nn];
    else             v = Wc1[(l * 256 + k) * 256 + nn];
  } else if (r < 393216) {     // Wn1, K=512 packed
    int rr = r - 262144;
    int ki = rr & 7, ln = (rr >> 3) & 63, f = rr >> 9;
    int ks = f & 15, n16 = f >> 4, al = ln & 15, ag = ln >> 4;
    int nn = n16 * 16 + al, k = ks * 32 + ag * 8 + ki;
    v = Wn1[(l * 512 + k) * 256 + nn];
  } else {                     // Wn2 packed + k-perm
    int rr = r - 393216;
    int ki = rr & 7, ln = (rr >> 3) & 63, f = rr >> 9;
    int ks = f & 7, n16 = f >> 3, al = ln & 15, ag = ln >> 4;
    int nn = n16 * 16 + al;
    int kslot = ks * 32 + ag * 8 + ki;
    int k = (kslot & ~63) | ((kslot & 3) << 4) | ((kslot & 63) >> 2);
    v = Wn2[(l * 256 + k) * 256 + nn];
  }
  wt[gid] = cvt1(v);
}

// ---------------- time embedding + preconditioning ----------------
__global__ __launch_bounds__(256) void embed_kernel(
    const float* __restrict__ logt, const float* __restrict__ xs,
    const float* __restrict__ Wemb, const float* __restrict__ bemb,
    float* __restrict__ h, float* __restrict__ x0) {
  __shared__ float te[128];
  const int b = blockIdx.x, tid = threadIdx.x;
  const float lt = logt[b];
  if (tid < 64) {
    float fr = powf(1e-4f, (float)tid * (1.0f / 64.0f));
    float ang = lt * 0.25f * fr;
    te[tid] = cosf(ang);
    te[tid + 64] = sinf(ang);
  }
  float tt = expf(lt);
  float cin = 1.0f / sqrtf(0.25f + tt * tt);
  if (tid < 192) x0[b * 192 + tid] = xs[b * 192 + tid] * cin;
  __syncthreads();
  float acc = bemb[tid];
  for (int k = 0; k < 128; ++k) acc += te[k] * Wemb[k * 256 + tid];
  float* hp = h + (b * 64) * 256 + tid;
#pragma unroll 4
  for (int nn = 0; nn < 64; ++nn) hp[nn * 256] = acc;
}

// ---------------- per-node projections: grid 128, packed-coalesced B ----------------
__global__ __launch_bounds__(256) void proj_kernel(
    const float* __restrict__ h, const ushort_t* __restrict__ Bt0,
    const ushort_t* __restrict__ Bt1, const float* __restrict__ be1,
    float* __restrict__ p_r, float* __restrict__ p_c) {
  __shared__ u32x4 AbV[64 * ASTR / 16];
  char* Ab = (char*)AbV;
  const int t = threadIdx.x, lane = t & 63, w = t >> 6;
  const int al = lane & 15, ag = lane >> 4;
  const int mat = blockIdx.x & 1;
  const int R0 = (blockIdx.x >> 1) * 64;
  {
    const int j = t & 63, cc = t >> 6;
    const float4* hv = (const float4*)(h + (R0 + j) * 256) + cc * 16;
    u32x4* wb = (u32x4*)(Ab + j * ASTR + cc * 128);
#pragma unroll
    for (int g = 0; g < 8; ++g) {
      float4 v0 = hv[g * 2], v1 = hv[g * 2 + 1];
      u32x4 q;
      q[0] = cvt2(v0.x, v0.y); q[1] = cvt2(v0.z, v0.w);
      q[2] = cvt2(v1.x, v1.y); q[3] = cvt2(v1.z, v1.w);
      wb[g] = q;
    }
  }
  __syncthreads();
  const char* Ath = Ab + al * ASTR + ag * 16;
  const char* Bth = (const char*)(mat ? Bt1 : Bt0) + w * 32768 + lane * 16;
  float* P = mat ? p_c : p_r;
  f4v acc[4][4];
#pragma unroll
  for (int mt = 0; mt < 4; ++mt)
#pragma unroll
    for (int nt = 0; nt < 4; ++nt) acc[mt][nt] = (f4v){0.f, 0.f, 0.f, 0.f};
  s8v b0[4], b1[4];
  loadB(b0, Bth, 0); loadB(b1, Bth, 1);
  mfma_step(Ath, 0, b0, acc); loadB(b0, Bth, 2);
  mfma_step(Ath, 1, b1, acc); loadB(b1, Bth, 3);
  mfma_step(Ath, 2, b0, acc); loadB(b0, Bth, 4);
  mfma_step(Ath, 3, b1, acc); loadB(b1, Bth, 5);
  mfma_step(Ath, 4, b0, acc); loadB(b0, Bth, 6);
  mfma_step(Ath, 5, b1, acc); loadB(b1, Bth, 7);
  mfma_step(Ath, 6, b0, acc);
  mfma_step(Ath, 7, b1, acc);
#pragma unroll
  for (int mt = 0; mt < 4; ++mt)
#pragma unroll
    for (int nt = 0; nt < 4; ++nt) {
      int col = w * 64 + nt * 16 + al;
      float bias = mat ? 0.0f : be1[col];
#pragma unroll
      for (int r = 0; r < 4; ++r) {
        int row = mt * 16 + ag * 4 + r;
        P[(R0 + row) * 256 + col] = acc[mt][nt][r] + bias;
      }
    }
}

// ---------------- fused edge kernel: one block per node (its 63 out-edges) ----------------
// 4 waves x 64 cols; packed-coalesced B; 2-deep pipeline; reg diet for 4 blocks/CU.
__global__ __launch_bounds__(256, 4) void edge_kernel(
    const float* __restrict__ x_in, float* __restrict__ x_out,
    const float* __restrict__ p_r, const float* __restrict__ p_c,
    const float* __restrict__ w_rad,
    const ushort_t* __restrict__ We2t, const float* __restrict__ be2,
    const float* __restrict__ Wa, const float* __restrict__ ba,
    const ushort_t* __restrict__ Wc1t, const float* __restrict__ bc1,
    const float* __restrict__ Wc2, ushort_t* __restrict__ aggb) {
  __shared__ u32x4 AbV[64 * ASTR / 16];   // 33 KB A-tile (m1, then m2)
  char* Ab = (char*)AbV;
  __shared__ float dn[64][3];
  __shared__ float red[4][64];

  const int t = threadIdx.x;
  const int node = ((blockIdx.x & 7) << 9) | (blockIdx.x >> 3);   // XCD swizzle
  const int b = node >> 6, n = node & 63;
  const int lane = t & 63, w = t >> 6;
  const int al = lane & 15, ag = lane >> 4;

  const char* bWe2 = (const char*)We2t + w * 32768 + lane * 16;
  const char* bWc1 = (const char*)Wc1t + w * 32768 + lane * 16;

  s8v b0[4], b1[4];
  loadB(b0, bWe2, 0);   // only panel 0 prefetched before phase 1 (reg diet)

  // ---- phase 1a: per-lane operand preload (coalesced) + geometry ----
  float4 pr4 = *(const float4*)(p_r + (node << 8) + 4 * lane);
  float4 wr4 = *(const float4*)(w_rad + 4 * lane);
  float r2_reg;
  {
    const int j = lane;
    const int cl = j < n ? j : j + 1;
    const int nb = (b << 6) + cl;
    const float xi0 = x_in[node * 3], xi1 = x_in[node * 3 + 1], xi2 = x_in[node * 3 + 2];
    const float d0 = xi0 - x_in[nb * 3], d1 = xi1 - x_in[nb * 3 + 1], d2 = xi2 - x_in[nb * 3 + 2];
    r2_reg = d0 * d0 + d1 * d1 + d2 * d2;
    if (w == 0 && j < 63) {
      const float inv = fast_rcp(sqrtf(r2_reg + 1e-8f) + 1.0f);
      dn[j][0] = d0 * inv; dn[j][1] = d1 * inv; dn[j][2] = d2 * inv;
    }
  }

  // ---- phase 1b: m1 rows w*16..+15 -> Ab; one coalesced p_c row-load per iter ----
  {
#pragma unroll
    for (int jj = 0; jj < 16; ++jj) {
      const int j = w * 16 + jj;
      u32x2 q2 = {0u, 0u};
      if (j < 63) {
        const int cl = j < n ? j : j + 1;
        const int nb = (b << 6) + cl;
        float4 pc4 = *(const float4*)(p_c + (nb << 8) + 4 * lane);
        const float rj = __shfl(r2_reg, j);
        float v0 = silu_f(pr4.x + pc4.x + rj * wr4.x);
        float v1 = silu_f(pr4.y + pc4.y + rj * wr4.y);
        float v2 = silu_f(pr4.z + pc4.z + rj * wr4.z);
        float v3 = silu_f(pr4.w + pc4.w + rj * wr4.w);
        q2[0] = cvt2(v0, v1); q2[1] = cvt2(v2, v3);
      }
      *(u32x2*)(Ab + j * ASTR + lane * 8) = q2;
    }
  }
  __syncthreads();   // S1: m1 visible

  const char* Ath = Ab + al * ASTR + ag * 16;

  // ---- GEMM1: g1 = m1 @ We2 — 2-deep reg-pipelined coalesced B ----
  f4v acc[4][4];
#pragma unroll
  for (int mt = 0; mt < 4; ++mt)
#pragma unroll
    for (int nt = 0; nt < 4; ++nt) acc[mt][nt] = (f4v){0.f, 0.f, 0.f, 0.f};
  loadB(b1, bWe2, 1);
  mfma_step(Ath, 0, b0, acc); loadB(b0, bWe2, 2);
  mfma_step(Ath, 1, b1, acc); loadB(b1, bWe2, 3);
  mfma_step(Ath, 2, b0, acc); loadB(b0, bWe2, 4);
  mfma_step(Ath, 3, b1, acc); loadB(b1, bWe2, 5);
  mfma_step(Ath, 4, b0, acc); loadB(b0, bWe2, 6);
  mfma_step(Ath, 5, b1, acc); loadB(b1, bWe2, 7);
  mfma_step(Ath, 6, b0, acc);
  mfma_step(Ath, 7, b1, acc);

  // ---- epilogue1a (regs only): m2 = silu(g1+be2); attention partials + reduce ----
  {
    float bb2[4], wa4[4];
#pragma unroll
    for (int nt = 0; nt < 4; ++nt) {
      int col = w * 64 + nt * 16 + al;
      bb2[nt] = be2[col]; wa4[nt] = Wa[col];
    }
    float attp[4][4];
#pragma unroll
    for (int mt = 0; mt < 4; ++mt) {
#pragma unroll
      for (int r = 0; r < 4; ++r) attp[mt][r] = 0.0f;
#pragma unroll
      for (int nt = 0; nt < 4; ++nt) {
#pragma unroll
        for (int r = 0; r < 4; ++r) {
          float v = silu_f(acc[mt][nt][r] + bb2[nt]);
          acc[mt][nt][r] = v;
          attp[mt][r] += v * wa4[nt];
        }
      }
    }
#pragma unroll
    for (int off = 1; off < 16; off <<= 1)
#pragma unroll
      for (int mt = 0; mt < 4; ++mt)
#pragma unroll
        for (int r = 0; r < 4; ++r) attp[mt][r] += __shfl_xor(attp[mt][r], off);
    __syncthreads();   // S2: all waves done reading m1 from Ab
    // ---- epilogue1b: m2 -> Ab in k-PERMUTED slot order (b64 writes) ----
    char* mwb = Ab + (ag * 4) * ASTR + (w * 64 + al * 4) * 2;
#pragma unroll
    for (int mt = 0; mt < 4; ++mt)
#pragma unroll
      for (int r = 0; r < 4; ++r) {
        u32x2 p;
        p[0] = cvt2(acc[mt][0][r], acc[mt][1][r]);
        p[1] = cvt2(acc[mt][2][r], acc[mt][3][r]);
        *(u32x2*)(mwb + mt * ASTR16 + r * ASTR) = p;
      }
    if (al == 0) {
#pragma unroll
      for (int mt = 0; mt < 4; ++mt)
#pragma unroll
        for (int r = 0; r < 4; ++r) red[w][mt * 16 + ag * 4 + r] = attp[mt][r];
    }
  }
  __syncthreads();     // S3: m2 + red ready

  // ---- GEMM2 panel prefetch (issued here, overlaps att+agg section) ----
  loadB(b0, bWc1, 0);
  loadB(b1, bWc1, 1);

  // ---- attention gate: every wave computes att_reg redundantly ----
  float att_reg;
  {
    float s = red[0][lane] + red[1][lane] + red[2][lane] + red[3][lane] + ba[0];
    att_reg = (lane < 63) ? sigm_f(s) : 0.0f;
  }

  // ---- agg column sums (att via shfl); store bf16 ----
  {
    float aggp[4] = {0.f, 0.f, 0.f, 0.f};
#pragma unroll
    for (int mt = 0; mt < 4; ++mt) {
      float a0 = __shfl(att_reg, mt * 16 + ag * 4 + 0);
      float a1 = __shfl(att_reg, mt * 16 + ag * 4 + 1);
      float a2 = __shfl(att_reg, mt * 16 + ag * 4 + 2);
      float a3 = __shfl(att_reg, mt * 16 + ag * 4 + 3);
#pragma unroll
      for (int nt = 0; nt < 4; ++nt)
        aggp[nt] += a0 * acc[mt][nt][0] + a1 * acc[mt][nt][1] +
                    a2 * acc[mt][nt][2] + a3 * acc[mt][nt][3];
    }
#pragma unroll
    for (int nt = 0; nt < 4; ++nt) {
      aggp[nt] += __shfl_xor(aggp[nt], 16);
      aggp[nt] += __shfl_xor(aggp[nt], 32);
    }
    float avv = (ag == 0) ? aggp[0] : (ag == 1) ? aggp[1] : (ag == 2) ? aggp[2] : aggp[3];
    aggb[(node << 8) + w * 64 + lane] = cvt1(avv);
  }

  // ---- GEMM2: g2 = m2 @ Wc1 (k-permuted consistently), 2-deep ----
#pragma unroll
  for (int mt = 0; mt < 4; ++mt)
#pragma unroll
    for (int nt = 0; nt < 4; ++nt) acc[mt][nt] = (f4v){0.f, 0.f, 0.f, 0.f};
  mfma_step(Ath, 0, b0, acc); loadB(b0, bWc1, 2);
  mfma_step(Ath, 1, b1, acc); loadB(b1, bWc1, 3);
  mfma_step(Ath, 2, b0, acc); loadB(b0, bWc1, 4);
  mfma_step(Ath, 3, b1, acc); loadB(b1, bWc1, 5);
  mfma_step(Ath, 4, b0, acc); loadB(b0, bWc1, 6);
  mfma_step(Ath, 5, b1, acc); loadB(b1, bWc1, 7);
  mfma_step(Ath, 6, b0, acc);
  mfma_step(Ath, 7, b1, acc);

  // ---- epilogue 2: s = silu(att*g2 + bc1); tr-partials = s . Wc2 ----
  {
    float b3[4], wc4[4];
#pragma unroll
    for (int nt = 0; nt < 4; ++nt) {
      int col = w * 64 + nt * 16 + al;
      b3[nt] = bc1[col]; wc4[nt] = Wc2[col];
    }
    float trp[4][4];
#pragma unroll
    for (int mt = 0; mt < 4; ++mt) {
      float a0 = __shfl(att_reg, mt * 16 + ag * 4 + 0);
      float a1 = __shfl(att_reg, mt * 16 + ag * 4 + 1);
      float a2 = __shfl(att_reg, mt * 16 + ag * 4 + 2);
      float a3 = __shfl(att_reg, mt * 16 + ag * 4 + 3);
#pragma unroll
      for (int r = 0; r < 4; ++r) trp[mt][r] = 0.0f;
#pragma unroll
      for (int nt = 0; nt < 4; ++nt) {
        trp[mt][0] += silu_f(a0 * acc[mt][nt][0] + b3[nt]) * wc4[nt];
        trp[mt][1] += silu_f(a1 * acc[mt][nt][1] + b3[nt]) * wc4[nt];
        trp[mt][2] += silu_f(a2 * acc[mt][nt][2] + b3[nt]) * wc4[nt];
        trp[mt][3] += silu_f(a3 * acc[mt][nt][3] + b3[nt]) * wc4[nt];
      }
    }
#pragma unroll
    for (int off = 1; off < 16; off <<= 1)
#pragma unroll
      for (int mt = 0; mt < 4; ++mt)
#pragma unroll
        for (int r = 0; r < 4; ++r) trp[mt][r] += __shfl_xor(trp[mt][r], off);
    if (al == 0) {
#pragma unroll
      for (int mt = 0; mt < 4; ++mt)
#pragma unroll
        for (int r = 0; r < 4; ++r) red[w][mt * 16 + ag * 4 + r] = trp[mt][r];
    }
  }
  __syncthreads();     // S4 (last): red2 ready

  // ---- fused tail (wave 0 only) ----
  if (t < 64) {
    float s = red[0][t] + red[1][t] + red[2][t] + red[3][t];
    float vx = 0.f, vy = 0.f, vz = 0.f;
    if (t < 63) {
      float tj = tanhf(s) * CR_L;
      vx = dn[t][0] * tj; vy = dn[t][1] * tj; vz = dn[t][2] * tj;
    }
#pragma unroll
    for (int off = 1; off < 64; off <<= 1) {
      vx += __shfl_xor(vx, off);
      vy += __shfl_xor(vy, off);
      vz += __shfl_xor(vz, off);
    }
    if (t == 0) {
      x_out[node * 3 + 0] = x_in[node * 3 + 0] + vx;
      x_out[node * 3 + 1] = x_in[node * 3 + 1] + vy;
      x_out[node * 3 + 2] = x_in[node * 3 + 2] + vz;
    }
  }
}

// ---------------- node update: h += silu([h||agg]@Wn1+bn1)@Wn2+bn2 — M=32, grid 128 ----------------
__global__ __launch_bounds__(256) void node_kernel(
    float* __restrict__ h, const ushort_t* __restrict__ aggb,
    const ushort_t* __restrict__ Wn1t, const float* __restrict__ bn1,
    const ushort_t* __restrict__ Wn2t, const float* __restrict__ bn2) {
  __shared__ u32x4 AbV[32 * NSTR / 16];
  char* Ab = (char*)AbV;
  const int t = threadIdx.x, lane = t & 63, w = t >> 6;
  const int al = lane & 15, ag = lane >> 4;
  const int R0 = blockIdx.x * 32;
  {
    const int j = t & 31, cc = t >> 5;
#pragma unroll
    for (int g = 0; g < 8; ++g) {
      int c0 = cc * 64 + g * 8;
      u32x4 q;
      if (c0 < 256) {
        const float4* src = (const float4*)(h + (R0 + j) * 256 + c0);
        float4 v0 = src[0], v1 = src[1];
        q[0] = cvt2(v0.x, v0.y); q[1] = cvt2(v0.z, v0.w);
        q[2] = cvt2(v1.x, v1.y); q[3] = cvt2(v1.z, v1.w);
      } else {
        q = *(const u32x4*)(aggb + (R0 + j) * 256 + (c0 - 256));
      }
      *(u32x4*)(Ab + j * NSTR + c0 * 2) = q;
    }
  }
  __syncthreads();
  const char* AthN = Ab + al * NSTR + ag * 16;
  const char* bW1 = (const char*)Wn1t + w * 65536 + lane * 16;
  f4v acc[2][4];
#pragma unroll
  for (int mt = 0; mt < 2; ++mt)
#pragma unroll
    for (int nt = 0; nt < 4; ++nt) acc[mt][nt] = (f4v){0.f, 0.f, 0.f, 0.f};
  s8v b0[4], b1[4];
  loadBn1(b0, bW1, 0); loadBn1(b1, bW1, 1);
  mfma32_n1(AthN, 0, b0, acc);  loadBn1(b0, bW1, 2);
  mfma32_n1(AthN, 1, b1, acc);  loadBn1(b1, bW1, 3);
  mfma32_n1(AthN, 2, b0, acc);  loadBn1(b0, bW1, 4);
  mfma32_n1(AthN, 3, b1, acc);  loadBn1(b1, bW1, 5);
  mfma32_n1(AthN, 4, b0, acc);  loadBn1(b0, bW1, 6);
  mfma32_n1(AthN, 5, b1, acc);  loadBn1(b1, bW1, 7);
  mfma32_n1(AthN, 6, b0, acc);  loadBn1(b0, bW1, 8);
  mfma32_n1(AthN, 7, b1, acc);  loadBn1(b1, bW1, 9);
  mfma32_n1(AthN, 8, b0, acc);  loadBn1(b0, bW1, 10);
  mfma32_n1(AthN, 9, b1, acc);  loadBn1(b1, bW1, 11);
  mfma32_n1(AthN, 10, b0, acc); loadBn1(b0, bW1, 12);
  mfma32_n1(AthN, 11, b1, acc); loadBn1(b1, bW1, 13);
  mfma32_n1(AthN, 12, b0, acc); loadBn1(b0, bW1, 14);
  mfma32_n1(AthN, 13, b1, acc); loadBn1(b1, bW1, 15);
  mfma32_n1(AthN, 14, b0, acc);
  mfma32_n1(AthN, 15, b1, acc);
  __syncthreads();
  {
    float bn1c[4];
#pragma unroll
    for (int nt = 0; nt < 4; ++nt) bn1c[nt] = bn1[w * 64 + nt * 16 + al];
    char* mwb = Ab + (ag * 4) * ASTR + (w * 64 + al * 4) * 2;
#pragma unroll
    for (int mt = 0; mt < 2; ++mt)
#pragma unroll
      for (int r = 0; r < 4; ++r) {
        float s0 = silu_f(acc[mt][0][r] + bn1c[0]);
        float s1 = silu_f(acc[mt][1][r] + bn1c[1]);
        float s2 = silu_f(acc[mt][2][r] + bn1c[2]);
        float s3 = silu_f(acc[mt][3][r] + bn1c[3]);
        u32x2 p; p[0] = cvt2(s0, s1); p[1] = cvt2(s2, s3);
        *(u32x2*)(mwb + mt * ASTR16 + r * ASTR) = p;
      }
  }
  __syncthreads();
  const char* Ath2 = Ab + al * ASTR + ag * 16;
  const char* bW2 = (const char*)Wn2t + w * 32768 + lane * 16;
  f4v acc2[2][4];
#pragma unroll
  for (int mt = 0; mt < 2; ++mt)
#pragma unroll
    for (int nt = 0; nt < 4; ++nt) acc2[mt][nt] = (f4v){0.f, 0.f, 0.f, 0.f};
  loadB(b0, bW2, 0); loadB(b1, bW2, 1);
  mfma32_a(Ath2, 0, b0, acc2); loadB(b0, bW2, 2);
  mfma32_a(Ath2, 1, b1, acc2); loadB(b1, bW2, 3);
  mfma32_a(Ath2, 2, b0, acc2); loadB(b0, bW2, 4);
  mfma32_a(Ath2, 3, b1, acc2); loadB(b1, bW2, 5);
  mfma32_a(Ath2, 4, b0, acc2); loadB(b0, bW2, 6);
  mfma32_a(Ath2, 5, b1, acc2); loadB(b1, bW2, 7);
  mfma32_a(Ath2, 6, b0, acc2);
  mfma32_a(Ath2, 7, b1, acc2);
  {
    float bn2c[4];
#pragma unroll
    for (int nt = 0; nt < 4; ++nt) bn2c[nt] = bn2[w * 64 + nt * 16 + al];
#pragma unroll
    for (int mt = 0; mt < 2; ++mt)
#pragma unroll
      for (int nt = 0; nt < 4; ++nt) {
        int col = w * 64 + nt * 16 + al;
#pragma unroll
        for (int r = 0; r < 4; ++r) {
          int row = mt * 16 + ag * 4 + r;
          int idx = (R0 + row) * 256 + col;
          h[idx] = h[idx] + acc2[mt][nt][r] + bn2c[nt];
        }
      }
  }
}

// ---------------- final: CoG removal + EDM output scaling ----------------
__global__ __launch_bounds__(64) void final_kernel(
    const float* __restrict__ logt, const float* __restrict__ xs,
    const float* __restrict__ xf, const float* __restrict__ x0,
    float* __restrict__ out) {
  const int b = blockIdx.x, t = threadIdx.x;
  float lt = logt[b], tt = expf(lt);
  float denom = 0.25f + tt * tt;
  float s1 = 0.25f / denom;
  float s2 = 0.5f * tt / sqrtf(denom);
  int node = b * 64 + t;
  float v0 = xf[node * 3 + 0] - x0[node * 3 + 0];
  float v1 = xf[node * 3 + 1] - x0[node * 3 + 1];
  float v2 = xf[node * 3 + 2] - x0[node * 3 + 2];
  float m0 = v0, m1 = v1, m2 = v2;
#pragma unroll
  for (int off = 1; off < 64; off <<= 1) {
    m0 += __shfl_xor(m0, off);
    m1 += __shfl_xor(m1, off);
    m2 += __shfl_xor(m2, off);
  }
  m0 *= (1.0f / 64.0f); m1 *= (1.0f / 64.0f); m2 *= (1.0f / 64.0f);
  out[b * 192 + t * 3 + 0] = xs[b * 192 + t * 3 + 0] * s1 + (v0 - m0) * s2;
  out[b * 192 + t * 3 + 1] = xs[b * 192 + t * 3 + 1] * s1 + (v1 - m1) * s2;
  out[b * 192 + t * 3 + 2] = xs[b * 192 + t * 3 + 2] * s1 + (v2 - m2) * s2;
}

extern "C" void kernel_launch(void* const* d_in, const int* in_sizes, int n_in,
                              void* d_out, int out_size, void* d_ws, size_t ws_size,
                              hipStream_t stream) {
  const float* logt = (const float*)d_in[0];
  const float* xs   = (const float*)d_in[1];
  const float* Wemb = (const float*)d_in[2];
  const float* bemb = (const float*)d_in[3];
  const float* We1  = (const float*)d_in[4];
  const float* be1  = (const float*)d_in[5];
  const float* We2  = (const float*)d_in[6];
  const float* be2  = (const float*)d_in[7];
  const float* Wa   = (const float*)d_in[8];
  const float* ba   = (const float*)d_in[9];
  const float* Wn1  = (const float*)d_in[10];
  const float* bn1  = (const float*)d_in[11];
  const float* Wn2  = (const float*)d_in[12];
  const float* bn2  = (const float*)d_in[13];
  const float* Wc1  = (const float*)d_in[14];
  const float* bc1  = (const float*)d_in[15];
  const float* Wc2  = (const float*)d_in[16];
  float* out = (float*)d_out;

  float* h    = (float*)d_ws;            // 4096*256 f32
  float* pr   = h  + NNODE * HID;
  float* pc   = pr + NNODE * HID;
  ushort_t* aggb = (ushort_t*)(pc + NNODE * HID);   // 4096*256 bf16
  float* x0   = (float*)(aggb + NNODE * HID);
  float* x1   = x0 + 12288;
  float* x2   = x1 + 12288;
  ushort_t* wt = (ushort_t*)(x2 + 12288);   // 1376256 bf16

  wconv_kernel<<<5376, 256, 0, stream>>>(We1, We2, Wc1, Wn1, Wn2, wt);
  embed_kernel<<<64, 256, 0, stream>>>(logt, xs, Wemb, bemb, h, x0);

  const float* xin = x0;
  float* xout = x1;
  for (int l = 0; l < 3; ++l) {
    const ushort_t* wl = wt + l * 458752;
    proj_kernel<<<128, 256, 0, stream>>>(h, wl, wl + 65536, be1 + l * 256, pr, pc);
    edge_kernel<<<4096, 256, 0, stream>>>(
        xin, xout, pr, pc,
        We1 + (l * 513 + 512) * 256,
        wl + 131072, be2 + l * 256,
        Wa + l * 256, ba + l,
        wl + 196608, bc1 + l * 256, Wc2 + l * 256, aggb);
    node_kernel<<<128, 256, 0, stream>>>(h, aggb, wl + 262144, bn1 + l * 256,
                                         wl + 393216, bn2 + l * 256);
    if (l == 0) { xin = x1; xout = x2; }
    else if (l == 1) { xin = x2; xout = x1; }
  }
  final_kernel<<<64, 64, 0, stream>>>(logt, xs, x1, x0, out);
}

// Round 12
// 417.400 us; speedup vs baseline: 1.0118x; 1.0118x over previous
//
#include <hip/hip_runtime.h>

typedef unsigned short ushort_t;
typedef __attribute__((ext_vector_type(8))) short s8v;
typedef __attribute__((ext_vector_type(4))) float f4v;
typedef __attribute__((ext_vector_type(2))) unsigned int u32x2;
typedef __attribute__((ext_vector_type(4))) unsigned int u32x4;

#define NNODE 4096
#define HID 256
#define CR_L 5.0f      // COORDS_RANGE / L = 15/3
#define ASTR 528       // A-tile row stride in bytes (33*16: aligned, bank-uniform)
#define ASTR16 (16 * ASTR)
#define NSTR 1056      // node-kernel stage-1 stride (66*16)
#define NSTR16 (16 * NSTR)

__device__ __forceinline__ unsigned int cvt2(float lo, float hi) {
  unsigned int r;
  asm("v_cvt_pk_bf16_f32 %0, %1, %2" : "=v"(r) : "v"(lo), "v"(hi));
  return r;  // D[15:0]=lo, D[31:16]=hi, RNE
}
__device__ __forceinline__ ushort_t cvt1(float v) {
  unsigned int r;
  asm("v_cvt_pk_bf16_f32 %0, %1, %2" : "=v"(r) : "v"(v), "v"(v));
  return (ushort_t)r;
}
__device__ __forceinline__ float fast_rcp(float x) {
  float r;
  asm("v_rcp_f32 %0, %1" : "=v"(r) : "v"(x));
  return r;
}
__device__ __forceinline__ float silu_f(float v) { return v * fast_rcp(1.0f + __expf(-v)); }
__device__ __forceinline__ float sigm_f(float v) { return fast_rcp(1.0f + __expf(-v)); }

// ---- fragment-packed B loads (K=256): frag (n16=w*4+nt, ks=q) = 64 contiguous 16B chunks ----
__device__ __forceinline__ void loadB(s8v bd[4], const char* base, int q) {
#pragma unroll
  for (int nt = 0; nt < 4; ++nt)
    bd[nt] = *(const s8v*)(base + nt * 8192 + q * 1024);
}
// K=512 variant (Wn1)
__device__ __forceinline__ void loadBn1(s8v bd[4], const char* base, int q) {
#pragma unroll
  for (int nt = 0; nt < 4; ++nt)
    bd[nt] = *(const s8v*)(base + nt * 16384 + q * 1024);
}
// M=64 MFMA step
__device__ __forceinline__ void mfma_step(const char* Ath, int q, const s8v bc[4], f4v acc[4][4]) {
  s8v a[4];
#pragma unroll
  for (int mt = 0; mt < 4; ++mt)
    a[mt] = *(const s8v*)(Ath + mt * ASTR16 + q * 64);
#pragma unroll
  for (int mt = 0; mt < 4; ++mt)
#pragma unroll
    for (int nt = 0; nt < 4; ++nt)
      acc[mt][nt] = __builtin_amdgcn_mfma_f32_16x16x32_bf16(a[mt], bc[nt], acc[mt][nt], 0, 0, 0);
}
// M=32 MFMA steps (node)
__device__ __forceinline__ void mfma32_n1(const char* Ath, int q, const s8v bc[4], f4v acc[2][4]) {
  s8v a[2];
#pragma unroll
  for (int mt = 0; mt < 2; ++mt)
    a[mt] = *(const s8v*)(Ath + mt * NSTR16 + q * 64);
#pragma unroll
  for (int mt = 0; mt < 2; ++mt)
#pragma unroll
    for (int nt = 0; nt < 4; ++nt)
      acc[mt][nt] = __builtin_amdgcn_mfma_f32_16x16x32_bf16(a[mt], bc[nt], acc[mt][nt], 0, 0, 0);
}
__device__ __forceinline__ void mfma32_a(const char* Ath, int q, const s8v bc[4], f4v acc[2][4]) {
  s8v a[2];
#pragma unroll
  for (int mt = 0; mt < 2; ++mt)
    a[mt] = *(const s8v*)(Ath + mt * ASTR16 + q * 64);
#pragma unroll
  for (int mt = 0; mt < 2; ++mt)
#pragma unroll
    for (int nt = 0; nt < 4; ++nt)
      acc[mt][nt] = __builtin_amdgcn_mfma_f32_16x16x32_bf16(a[mt], bc[nt], acc[mt][nt], 0, 0, 0);
}

// ---------------- weight transpose + bf16 convert (ALL fragment-packed) ----------------
// per layer: [0]We1r [64K]We1c [128K]We2 [192K]Wc1(k-perm) [256K]Wn1(K=512) [384K]Wn2(k-perm)
__global__ __launch_bounds__(256) void wconv_kernel(
    const float* __restrict__ We1, const float* __restrict__ We2,
    const float* __restrict__ Wc1, const float* __restrict__ Wn1,
    const float* __restrict__ Wn2, ushort_t* __restrict__ wt) {
  int gid = blockIdx.x * 256 + threadIdx.x;          // < 1376256
  int l = gid / 458752;
  int r = gid - l * 458752;
  float v;
  if (r < 262144) {            // four K=256 mats: We1r, We1c, We2, Wc1
    int m = r >> 16;           // 0..3
    int rr = r & 65535;
    int ki = rr & 7, ln = (rr >> 3) & 63, f = rr >> 9;
    int ks = f & 7, n16 = f >> 3, al = ln & 15, ag = ln >> 4;
    int nn = n16 * 16 + al;
    int kslot = ks * 32 + ag * 8 + ki;
    int k = (m == 3) ? ((kslot & ~63) | ((kslot & 3) << 4) | ((kslot & 63) >> 2)) : kslot;
    if (m == 0)      v = We1[(l * 513 + k) * 256 + nn];
    else if (m == 1) v = We1[(l * 513 + 256 + k) * 256 + nn];
    else if (m == 2) v = We2[(l * 256 + k) * 256 + nn];
    else             v = Wc1[(l * 256 + k) * 256 + nn];
  } else if (r < 393216) {     // Wn1, K=512 packed: f = n16*16+ks
    int rr = r - 262144;
    int ki = rr & 7, ln = (rr >> 3) & 63, f = rr >> 9;     // f in [0,256)
    int ks = f & 15, n16 = f >> 4, al = ln & 15, ag = ln >> 4;
    int nn = n16 * 16 + al, k = ks * 32 + ag * 8 + ki;
    v = Wn1[(l * 512 + k) * 256 + nn];
  } else {                     // Wn2 packed + k-perm
    int rr = r - 393216;
    int ki = rr & 7, ln = (rr >> 3) & 63, f = rr >> 9;
    int ks = f & 7, n16 = f >> 3, al = ln & 15, ag = ln >> 4;
    int nn = n16 * 16 + al;
    int kslot = ks * 32 + ag * 8 + ki;
    int k = (kslot & ~63) | ((kslot & 3) << 4) | ((kslot & 63) >> 2);
    v = Wn2[(l * 256 + k) * 256 + nn];
  }
  wt[gid] = cvt1(v);
}

// ---------------- time embedding + preconditioning ----------------
__global__ __launch_bounds__(256) void embed_kernel(
    const float* __restrict__ logt, const float* __restrict__ xs,
    const float* __restrict__ Wemb, const float* __restrict__ bemb,
    float* __restrict__ h, float* __restrict__ x0) {
  __shared__ float te[128];
  const int b = blockIdx.x, tid = threadIdx.x;
  const float lt = logt[b];
  if (tid < 64) {
    float fr = powf(1e-4f, (float)tid * (1.0f / 64.0f));
    float ang = lt * 0.25f * fr;
    te[tid] = cosf(ang);
    te[tid + 64] = sinf(ang);
  }
  float tt = expf(lt);
  float cin = 1.0f / sqrtf(0.25f + tt * tt);
  if (tid < 192) x0[b * 192 + tid] = xs[b * 192 + tid] * cin;
  __syncthreads();
  float acc = bemb[tid];
  for (int k = 0; k < 128; ++k) acc += te[k] * Wemb[k * 256 + tid];
  float* hp = h + (b * 64) * 256 + tid;
#pragma unroll 4
  for (int nn = 0; nn < 64; ++nn) hp[nn * 256] = acc;
}

// ---------------- per-node projections: grid 128, packed-coalesced B ----------------
__global__ __launch_bounds__(256) void proj_kernel(
    const float* __restrict__ h, const ushort_t* __restrict__ Bt0,
    const ushort_t* __restrict__ Bt1, const float* __restrict__ be1,
    float* __restrict__ p_r, float* __restrict__ p_c) {
  __shared__ u32x4 AbV[64 * ASTR / 16];
  char* Ab = (char*)AbV;
  const int t = threadIdx.x, lane = t & 63, w = t >> 6;
  const int al = lane & 15, ag = lane >> 4;
  const int mat = blockIdx.x & 1;
  const int R0 = (blockIdx.x >> 1) * 64;
  {
    const int j = t & 63, cc = t >> 6;
    const float4* hv = (const float4*)(h + (R0 + j) * 256) + cc * 16;
    u32x4* wb = (u32x4*)(Ab + j * ASTR + cc * 128);
#pragma unroll
    for (int g = 0; g < 8; ++g) {
      float4 v0 = hv[g * 2], v1 = hv[g * 2 + 1];
      u32x4 q;
      q[0] = cvt2(v0.x, v0.y); q[1] = cvt2(v0.z, v0.w);
      q[2] = cvt2(v1.x, v1.y); q[3] = cvt2(v1.z, v1.w);
      wb[g] = q;
    }
  }
  __syncthreads();
  const char* Ath = Ab + al * ASTR + ag * 16;
  const char* Bth = (const char*)(mat ? Bt1 : Bt0) + w * 32768 + lane * 16;
  float* P = mat ? p_c : p_r;
  f4v acc[4][4];
#pragma unroll
  for (int mt = 0; mt < 4; ++mt)
#pragma unroll
    for (int nt = 0; nt < 4; ++nt) acc[mt][nt] = (f4v){0.f, 0.f, 0.f, 0.f};
  s8v b0[4], b1[4];
  loadB(b0, Bth, 0); loadB(b1, Bth, 1);
  mfma_step(Ath, 0, b0, acc); loadB(b0, Bth, 2);
  mfma_step(Ath, 1, b1, acc); loadB(b1, Bth, 3);
  mfma_step(Ath, 2, b0, acc); loadB(b0, Bth, 4);
  mfma_step(Ath, 3, b1, acc); loadB(b1, Bth, 5);
  mfma_step(Ath, 4, b0, acc); loadB(b0, Bth, 6);
  mfma_step(Ath, 5, b1, acc); loadB(b1, Bth, 7);
  mfma_step(Ath, 6, b0, acc);
  mfma_step(Ath, 7, b1, acc);
#pragma unroll
  for (int mt = 0; mt < 4; ++mt)
#pragma unroll
    for (int nt = 0; nt < 4; ++nt) {
      int col = w * 64 + nt * 16 + al;
      float bias = mat ? 0.0f : be1[col];
#pragma unroll
      for (int r = 0; r < 4; ++r) {
        int row = mt * 16 + ag * 4 + r;
        P[(R0 + row) * 256 + col] = acc[mt][nt][r] + bias;
      }
    }
}

// ---------------- fused edge kernel: one block per node (its 63 out-edges) ----------------
// 4 waves x 64 cols; packed-coalesced B; k-perm b64 m2 writeback; XCD swizzle. (R10 optimum)
__global__ __launch_bounds__(256, 3) void edge_kernel(
    const float* __restrict__ x_in, float* __restrict__ x_out,
    const float* __restrict__ p_r, const float* __restrict__ p_c,
    const float* __restrict__ w_rad,
    const ushort_t* __restrict__ We2t, const float* __restrict__ be2,
    const float* __restrict__ Wa, const float* __restrict__ ba,
    const ushort_t* __restrict__ Wc1t, const float* __restrict__ bc1,
    const float* __restrict__ Wc2, ushort_t* __restrict__ aggb) {
  __shared__ u32x4 AbV[64 * ASTR / 16];   // 33 KB A-tile (m1, then m2)
  char* Ab = (char*)AbV;
  __shared__ float dn[64][3];
  __shared__ float red[4][64];

  const int t = threadIdx.x;
  const int node = ((blockIdx.x & 7) << 9) | (blockIdx.x >> 3);   // XCD swizzle
  const int b = node >> 6, n = node & 63;
  const int lane = t & 63, w = t >> 6;
  const int al = lane & 15, ag = lane >> 4;

  const char* bWe2 = (const char*)We2t + w * 32768 + lane * 16;
  const char* bWc1 = (const char*)Wc1t + w * 32768 + lane * 16;

  s8v b0[4], b1[4], b2[4];
  loadB(b0, bWe2, 0);
  loadB(b1, bWe2, 1);

  // ---- phase 1a: per-lane operand preload (coalesced) + geometry ----
  float4 pr4 = *(const float4*)(p_r + (node << 8) + 4 * lane);
  float4 wr4 = *(const float4*)(w_rad + 4 * lane);
  float r2_reg;
  {
    const int j = lane;
    const int cl = j < n ? j : j + 1;
    const int nb = (b << 6) + cl;
    const float xi0 = x_in[node * 3], xi1 = x_in[node * 3 + 1], xi2 = x_in[node * 3 + 2];
    const float d0 = xi0 - x_in[nb * 3], d1 = xi1 - x_in[nb * 3 + 1], d2 = xi2 - x_in[nb * 3 + 2];
    r2_reg = d0 * d0 + d1 * d1 + d2 * d2;
    if (w == 0 && j < 63) {
      const float inv = fast_rcp(sqrtf(r2_reg + 1e-8f) + 1.0f);
      dn[j][0] = d0 * inv; dn[j][1] = d1 * inv; dn[j][2] = d2 * inv;
    }
  }

  // ---- phase 1b: m1 rows w*16..+15 -> Ab; one coalesced p_c row-load per iter ----
  {
#pragma unroll
    for (int jj = 0; jj < 16; ++jj) {
      const int j = w * 16 + jj;
      u32x2 q2 = {0u, 0u};
      if (j < 63) {
        const int cl = j < n ? j : j + 1;
        const int nb = (b << 6) + cl;
        float4 pc4 = *(const float4*)(p_c + (nb << 8) + 4 * lane);
        const float rj = __shfl(r2_reg, j);
        float v0 = silu_f(pr4.x + pc4.x + rj * wr4.x);
        float v1 = silu_f(pr4.y + pc4.y + rj * wr4.y);
        float v2 = silu_f(pr4.z + pc4.z + rj * wr4.z);
        float v3 = silu_f(pr4.w + pc4.w + rj * wr4.w);
        q2[0] = cvt2(v0, v1); q2[1] = cvt2(v2, v3);
      }
      *(u32x2*)(Ab + j * ASTR + lane * 8) = q2;
    }
  }
  __syncthreads();   // S1: m1 visible

  const char* Ath = Ab + al * ASTR + ag * 16;

  // ---- GEMM1: g1 = m1 @ We2 — 3-deep reg-pipelined coalesced B ----
  f4v acc[4][4];
#pragma unroll
  for (int mt = 0; mt < 4; ++mt)
#pragma unroll
    for (int nt = 0; nt < 4; ++nt) acc[mt][nt] = (f4v){0.f, 0.f, 0.f, 0.f};
  loadB(b2, bWe2, 2); mfma_step(Ath, 0, b0, acc);
  loadB(b0, bWe2, 3); mfma_step(Ath, 1, b1, acc);
  loadB(b1, bWe2, 4); mfma_step(Ath, 2, b2, acc);
  loadB(b2, bWe2, 5); mfma_step(Ath, 3, b0, acc);
  loadB(b0, bWe2, 6); mfma_step(Ath, 4, b1, acc);
  loadB(b1, bWe2, 7); mfma_step(Ath, 5, b2, acc);
  loadB(b2, bWc1, 0); mfma_step(Ath, 6, b0, acc);
  loadB(b0, bWc1, 1); mfma_step(Ath, 7, b1, acc);

  // ---- epilogue1a (regs only): m2 = silu(g1+be2); attention partials + reduce ----
  {
    float bb2[4], wa4[4];
#pragma unroll
    for (int nt = 0; nt < 4; ++nt) {
      int col = w * 64 + nt * 16 + al;
      bb2[nt] = be2[col]; wa4[nt] = Wa[col];
    }
    float attp[4][4];
#pragma unroll
    for (int mt = 0; mt < 4; ++mt) {
#pragma unroll
      for (int r = 0; r < 4; ++r) attp[mt][r] = 0.0f;
#pragma unroll
      for (int nt = 0; nt < 4; ++nt) {
#pragma unroll
        for (int r = 0; r < 4; ++r) {
          float v = silu_f(acc[mt][nt][r] + bb2[nt]);
          acc[mt][nt][r] = v;
          attp[mt][r] += v * wa4[nt];
        }
      }
    }
#pragma unroll
    for (int off = 1; off < 16; off <<= 1)
#pragma unroll
      for (int mt = 0; mt < 4; ++mt)
#pragma unroll
        for (int r = 0; r < 4; ++r) attp[mt][r] += __shfl_xor(attp[mt][r], off);
    __syncthreads();   // S2: all waves done reading m1 from Ab
    // ---- epilogue1b: m2 -> Ab in k-PERMUTED slot order (b64 writes, matches Wc1t perm) ----
    char* mwb = Ab + (ag * 4) * ASTR + (w * 64 + al * 4) * 2;
#pragma unroll
    for (int mt = 0; mt < 4; ++mt)
#pragma unroll
      for (int r = 0; r < 4; ++r) {
        u32x2 p;
        p[0] = cvt2(acc[mt][0][r], acc[mt][1][r]);
        p[1] = cvt2(acc[mt][2][r], acc[mt][3][r]);
        *(u32x2*)(mwb + mt * ASTR16 + r * ASTR) = p;
      }
    if (al == 0) {
#pragma unroll
      for (int mt = 0; mt < 4; ++mt)
#pragma unroll
        for (int r = 0; r < 4; ++r) red[w][mt * 16 + ag * 4 + r] = attp[mt][r];
    }
  }
  __syncthreads();     // S3: m2 + red ready

  // ---- attention gate: every wave computes att_reg redundantly ----
  float att_reg;
  {
    float s = red[0][lane] + red[1][lane] + red[2][lane] + red[3][lane] + ba[0];
    att_reg = (lane < 63) ? sigm_f(s) : 0.0f;
  }

  // ---- agg column sums (att via shfl); store bf16 ----
  {
    float aggp[4] = {0.f, 0.f, 0.f, 0.f};
#pragma unroll
    for (int mt = 0; mt < 4; ++mt) {
      float a0 = __shfl(att_reg, mt * 16 + ag * 4 + 0);
      float a1 = __shfl(att_reg, mt * 16 + ag * 4 + 1);
      float a2 = __shfl(att_reg, mt * 16 + ag * 4 + 2);
      float a3 = __shfl(att_reg, mt * 16 + ag * 4 + 3);
#pragma unroll
      for (int nt = 0; nt < 4; ++nt)
        aggp[nt] += a0 * acc[mt][nt][0] + a1 * acc[mt][nt][1] +
                    a2 * acc[mt][nt][2] + a3 * acc[mt][nt][3];
    }
#pragma unroll
    for (int nt = 0; nt < 4; ++nt) {
      aggp[nt] += __shfl_xor(aggp[nt], 16);
      aggp[nt] += __shfl_xor(aggp[nt], 32);
    }
    float avv = (ag == 0) ? aggp[0] : (ag == 1) ? aggp[1] : (ag == 2) ? aggp[2] : aggp[3];
    aggb[(node << 8) + w * 64 + lane] = cvt1(avv);
  }

  // ---- GEMM2: g2 = m2 @ Wc1 (both k-permuted consistently) ----
#pragma unroll
  for (int mt = 0; mt < 4; ++mt)
#pragma unroll
    for (int nt = 0; nt < 4; ++nt) acc[mt][nt] = (f4v){0.f, 0.f, 0.f, 0.f};
  loadB(b1, bWc1, 2); mfma_step(Ath, 0, b2, acc);
  loadB(b2, bWc1, 3); mfma_step(Ath, 1, b0, acc);
  loadB(b0, bWc1, 4); mfma_step(Ath, 2, b1, acc);
  loadB(b1, bWc1, 5); mfma_step(Ath, 3, b2, acc);
  loadB(b2, bWc1, 6); mfma_step(Ath, 4, b0, acc);
  loadB(b0, bWc1, 7); mfma_step(Ath, 5, b1, acc);
  mfma_step(Ath, 6, b2, acc);
  mfma_step(Ath, 7, b0, acc);

  // ---- epilogue 2: s = silu(att*g2 + bc1); tr-partials = s . Wc2 ----
  {
    float b3[4], wc4[4];
#pragma unroll
    for (int nt = 0; nt < 4; ++nt) {
      int col = w * 64 + nt * 16 + al;
      b3[nt] = bc1[col]; wc4[nt] = Wc2[col];
    }
    float trp[4][4];
#pragma unroll
    for (int mt = 0; mt < 4; ++mt) {
      float a0 = __shfl(att_reg, mt * 16 + ag * 4 + 0);
      float a1 = __shfl(att_reg, mt * 16 + ag * 4 + 1);
      float a2 = __shfl(att_reg, mt * 16 + ag * 4 + 2);
      float a3 = __shfl(att_reg, mt * 16 + ag * 4 + 3);
#pragma unroll
      for (int r = 0; r < 4; ++r) trp[mt][r] = 0.0f;
#pragma unroll
      for (int nt = 0; nt < 4; ++nt) {
        trp[mt][0] += silu_f(a0 * acc[mt][nt][0] + b3[nt]) * wc4[nt];
        trp[mt][1] += silu_f(a1 * acc[mt][nt][1] + b3[nt]) * wc4[nt];
        trp[mt][2] += silu_f(a2 * acc[mt][nt][2] + b3[nt]) * wc4[nt];
        trp[mt][3] += silu_f(a3 * acc[mt][nt][3] + b3[nt]) * wc4[nt];
      }
    }
#pragma unroll
    for (int off = 1; off < 16; off <<= 1)
#pragma unroll
      for (int mt = 0; mt < 4; ++mt)
#pragma unroll
        for (int r = 0; r < 4; ++r) trp[mt][r] += __shfl_xor(trp[mt][r], off);
    if (al == 0) {
#pragma unroll
      for (int mt = 0; mt < 4; ++mt)
#pragma unroll
        for (int r = 0; r < 4; ++r) red[w][mt * 16 + ag * 4 + r] = trp[mt][r];
    }
  }
  __syncthreads();     // S4 (last): red2 ready

  // ---- fused tail (wave 0 only) ----
  if (t < 64) {
    float s = red[0][t] + red[1][t] + red[2][t] + red[3][t];
    float vx = 0.f, vy = 0.f, vz = 0.f;
    if (t < 63) {
      float tj = tanhf(s) * CR_L;
      vx = dn[t][0] * tj; vy = dn[t][1] * tj; vz = dn[t][2] * tj;
    }
#pragma unroll
    for (int off = 1; off < 64; off <<= 1) {
      vx += __shfl_xor(vx, off);
      vy += __shfl_xor(vy, off);
      vz += __shfl_xor(vz, off);
    }
    if (t == 0) {
      x_out[node * 3 + 0] = x_in[node * 3 + 0] + vx;
      x_out[node * 3 + 1] = x_in[node * 3 + 1] + vy;
      x_out[node * 3 + 2] = x_in[node * 3 + 2] + vz;
    }
  }
}

// ---------------- node update: h += silu([h||agg]@Wn1+bn1)@Wn2+bn2 — M=32, grid 128 ----------------
__global__ __launch_bounds__(256) void node_kernel(
    float* __restrict__ h, const ushort_t* __restrict__ aggb,
    const ushort_t* __restrict__ Wn1t, const float* __restrict__ bn1,
    const ushort_t* __restrict__ Wn2t, const float* __restrict__ bn2) {
  __shared__ u32x4 AbV[32 * NSTR / 16];   // 33KB: A1 [32][512]@1056B, reused as A2 [32][256]@528B
  char* Ab = (char*)AbV;
  const int t = threadIdx.x, lane = t & 63, w = t >> 6;
  const int al = lane & 15, ag = lane >> 4;
  const int R0 = blockIdx.x * 32;
  {
    const int j = t & 31, cc = t >> 5;   // 8 col-groups of 64
#pragma unroll
    for (int g = 0; g < 8; ++g) {
      int c0 = cc * 64 + g * 8;
      u32x4 q;
      if (c0 < 256) {
        const float4* src = (const float4*)(h + (R0 + j) * 256 + c0);
        float4 v0 = src[0], v1 = src[1];
        q[0] = cvt2(v0.x, v0.y); q[1] = cvt2(v0.z, v0.w);
        q[2] = cvt2(v1.x, v1.y); q[3] = cvt2(v1.z, v1.w);
      } else {
        q = *(const u32x4*)(aggb + (R0 + j) * 256 + (c0 - 256));
      }
      *(u32x4*)(Ab + j * NSTR + c0 * 2) = q;
    }
  }
  __syncthreads();
  // GEMM-A: K=512, packed Wn1
  const char* AthN = Ab + al * NSTR + ag * 16;
  const char* bW1 = (const char*)Wn1t + w * 65536 + lane * 16;
  f4v acc[2][4];
#pragma unroll
  for (int mt = 0; mt < 2; ++mt)
#pragma unroll
    for (int nt = 0; nt < 4; ++nt) acc[mt][nt] = (f4v){0.f, 0.f, 0.f, 0.f};
  s8v b0[4], b1[4];
  loadBn1(b0, bW1, 0); loadBn1(b1, bW1, 1);
  mfma32_n1(AthN, 0, b0, acc);  loadBn1(b0, bW1, 2);
  mfma32_n1(AthN, 1, b1, acc);  loadBn1(b1, bW1, 3);
  mfma32_n1(AthN, 2, b0, acc);  loadBn1(b0, bW1, 4);
  mfma32_n1(AthN, 3, b1, acc);  loadBn1(b1, bW1, 5);
  mfma32_n1(AthN, 4, b0, acc);  loadBn1(b0, bW1, 6);
  mfma32_n1(AthN, 5, b1, acc);  loadBn1(b1, bW1, 7);
  mfma32_n1(AthN, 6, b0, acc);  loadBn1(b0, bW1, 8);
  mfma32_n1(AthN, 7, b1, acc);  loadBn1(b1, bW1, 9);
  mfma32_n1(AthN, 8, b0, acc);  loadBn1(b0, bW1, 10);
  mfma32_n1(AthN, 9, b1, acc);  loadBn1(b1, bW1, 11);
  mfma32_n1(AthN, 10, b0, acc); loadBn1(b0, bW1, 12);
  mfma32_n1(AthN, 11, b1, acc); loadBn1(b1, bW1, 13);
  mfma32_n1(AthN, 12, b0, acc); loadBn1(b0, bW1, 14);
  mfma32_n1(AthN, 13, b1, acc); loadBn1(b1, bW1, 15);
  mfma32_n1(AthN, 14, b0, acc);
  mfma32_n1(AthN, 15, b1, acc);
  __syncthreads();
  // u = silu(. + bn1) -> A2, k-PERMUTED slot order (matches Wn2t perm), b64 writes
  {
    float bn1c[4];
#pragma unroll
    for (int nt = 0; nt < 4; ++nt) bn1c[nt] = bn1[w * 64 + nt * 16 + al];
    char* mwb = Ab + (ag * 4) * ASTR + (w * 64 + al * 4) * 2;
#pragma unroll
    for (int mt = 0; mt < 2; ++mt)
#pragma unroll
      for (int r = 0; r < 4; ++r) {
        float s0 = silu_f(acc[mt][0][r] + bn1c[0]);
        float s1 = silu_f(acc[mt][1][r] + bn1c[1]);
        float s2 = silu_f(acc[mt][2][r] + bn1c[2]);
        float s3 = silu_f(acc[mt][3][r] + bn1c[3]);
        u32x2 p; p[0] = cvt2(s0, s1); p[1] = cvt2(s2, s3);
        *(u32x2*)(mwb + mt * ASTR16 + r * ASTR) = p;
      }
  }
  __syncthreads();
  // GEMM-B + residual (packed+perm Wn2)
  const char* Ath2 = Ab + al * ASTR + ag * 16;
  const char* bW2 = (const char*)Wn2t + w * 32768 + lane * 16;
  f4v acc2[2][4];
#pragma unroll
  for (int mt = 0; mt < 2; ++mt)
#pragma unroll
    for (int nt = 0; nt < 4; ++nt) acc2[mt][nt] = (f4v){0.f, 0.f, 0.f, 0.f};
  loadB(b0, bW2, 0); loadB(b1, bW2, 1);
  mfma32_a(Ath2, 0, b0, acc2); loadB(b0, bW2, 2);
  mfma32_a(Ath2, 1, b1, acc2); loadB(b1, bW2, 3);
  mfma32_a(Ath2, 2, b0, acc2); loadB(b0, bW2, 4);
  mfma32_a(Ath2, 3, b1, acc2); loadB(b1, bW2, 5);
  mfma32_a(Ath2, 4, b0, acc2); loadB(b0, bW2, 6);
  mfma32_a(Ath2, 5, b1, acc2); loadB(b1, bW2, 7);
  mfma32_a(Ath2, 6, b0, acc2);
  mfma32_a(Ath2, 7, b1, acc2);
  {
    float bn2c[4];
#pragma unroll
    for (int nt = 0; nt < 4; ++nt) bn2c[nt] = bn2[w * 64 + nt * 16 + al];
#pragma unroll
    for (int mt = 0; mt < 2; ++mt)
#pragma unroll
      for (int nt = 0; nt < 4; ++nt) {
        int col = w * 64 + nt * 16 + al;
#pragma unroll
        for (int r = 0; r < 4; ++r) {
          int row = mt * 16 + ag * 4 + r;
          int idx = (R0 + row) * 256 + col;
          h[idx] = h[idx] + acc2[mt][nt][r] + bn2c[nt];
        }
      }
  }
}

// ---------------- final: CoG removal + EDM output scaling ----------------
__global__ __launch_bounds__(64) void final_kernel(
    const float* __restrict__ logt, const float* __restrict__ xs,
    const float* __restrict__ xf, const float* __restrict__ x0,
    float* __restrict__ out) {
  const int b = blockIdx.x, t = threadIdx.x;
  float lt = logt[b], tt = expf(lt);
  float denom = 0.25f + tt * tt;
  float s1 = 0.25f / denom;
  float s2 = 0.5f * tt / sqrtf(denom);
  int node = b * 64 + t;
  float v0 = xf[node * 3 + 0] - x0[node * 3 + 0];
  float v1 = xf[node * 3 + 1] - x0[node * 3 + 1];
  float v2 = xf[node * 3 + 2] - x0[node * 3 + 2];
  float m0 = v0, m1 = v1, m2 = v2;
#pragma unroll
  for (int off = 1; off < 64; off <<= 1) {
    m0 += __shfl_xor(m0, off);
    m1 += __shfl_xor(m1, off);
    m2 += __shfl_xor(m2, off);
  }
  m0 *= (1.0f / 64.0f); m1 *= (1.0f / 64.0f); m2 *= (1.0f / 64.0f);
  out[b * 192 + t * 3 + 0] = xs[b * 192 + t * 3 + 0] * s1 + (v0 - m0) * s2;
  out[b * 192 + t * 3 + 1] = xs[b * 192 + t * 3 + 1] * s1 + (v1 - m1) * s2;
  out[b * 192 + t * 3 + 2] = xs[b * 192 + t * 3 + 2] * s1 + (v2 - m2) * s2;
}

extern "C" void kernel_launch(void* const* d_in, const int* in_sizes, int n_in,
                              void* d_out, int out_size, void* d_ws, size_t ws_size,
                              hipStream_t stream) {
  const float* logt = (const float*)d_in[0];
  const float* xs   = (const float*)d_in[1];
  const float* Wemb = (const float*)d_in[2];
  const float* bemb = (const float*)d_in[3];
  const float* We1  = (const float*)d_in[4];
  const float* be1  = (const float*)d_in[5];
  const float* We2  = (const float*)d_in[6];
  const float* be2  = (const float*)d_in[7];
  const float* Wa   = (const float*)d_in[8];
  const float* ba   = (const float*)d_in[9];
  const float* Wn1  = (const float*)d_in[10];
  const float* bn1  = (const float*)d_in[11];
  const float* Wn2  = (const float*)d_in[12];
  const float* bn2  = (const float*)d_in[13];
  const float* Wc1  = (const float*)d_in[14];
  const float* bc1  = (const float*)d_in[15];
  const float* Wc2  = (const float*)d_in[16];
  float* out = (float*)d_out;

  float* h    = (float*)d_ws;            // 4096*256 f32
  float* pr   = h  + NNODE * HID;
  float* pc   = pr + NNODE * HID;
  ushort_t* aggb = (ushort_t*)(pc + NNODE * HID);   // 4096*256 bf16
  float* x0   = (float*)(aggb + NNODE * HID);
  float* x1   = x0 + 12288;
  float* x2   = x1 + 12288;
  ushort_t* wt = (ushort_t*)(x2 + 12288);   // 1376256 bf16

  wconv_kernel<<<5376, 256, 0, stream>>>(We1, We2, Wc1, Wn1, Wn2, wt);
  embed_kernel<<<64, 256, 0, stream>>>(logt, xs, Wemb, bemb, h, x0);

  const float* xin = x0;
  float* xout = x1;
  for (int l = 0; l < 3; ++l) {
    const ushort_t* wl = wt + l * 458752;
    proj_kernel<<<128, 256, 0, stream>>>(h, wl, wl + 65536, be1 + l * 256, pr, pc);
    edge_kernel<<<4096, 256, 0, stream>>>(
        xin, xout, pr, pc,
        We1 + (l * 513 + 512) * 256,
        wl + 131072, be2 + l * 256,
        Wa + l * 256, ba + l,
        wl + 196608, bc1 + l * 256, Wc2 + l * 256, aggb);
    node_kernel<<<128, 256, 0, stream>>>(h, aggb, wl + 262144, bn1 + l * 256,
                                         wl + 393216, bn2 + l * 256);
    if (l == 0) { xin = x1; xout = x2; }
    else if (l == 1) { xin = x2; xout = x1; }
  }
  final_kernel<<<64, 64, 0, stream>>>(logt, xs, x1, x0, out);
}